// Round 1
// baseline (510.016 us; speedup 1.0000x reference)
//
#include <hip/hip_runtime.h>
#include <math.h>

#define BB 32
#define MM 2048
#define NN 512
#define PSZ 16
#define HH 640
#define WW 640
#define DD 256
#define DIMG_ 384
#define NHEADS 8
#define PD_ 768
#define TWO_N 1024
#define ROWS_TOT (BB * TWO_N)          // 32768 patch rows
#define CHCT 16                        // ctx key-chunks per batch

typedef short bf16x8 __attribute__((ext_vector_type(8)));
typedef float f32x4  __attribute__((ext_vector_type(4)));

// ---- fp32 -> bf16 (RNE) helpers -------------------------------------------
__device__ __forceinline__ unsigned short f2bf(float x) {
  unsigned int u = __float_as_uint(x);
  u = (u + 0x7FFF + ((u >> 16) & 1)) >> 16;
  return (unsigned short)u;
}
__device__ __forceinline__ float bf2f(unsigned short h) {
  return __uint_as_float(((unsigned int)h) << 16);
}

// ---- async global->LDS (16B per lane, lds base must be wave-uniform) ------
__device__ __forceinline__ void gload_lds16(const void* g, void* l) {
  __builtin_amdgcn_global_load_lds(
      (const __attribute__((address_space(1))) void*)g,
      (__attribute__((address_space(3))) void*)l, 16, 0, 0);
}

// ---------------------------------------------------------------------------
// Kernel 1 (fused prep + extract):
//   blocks [0,768)   : W_pe -> Whi/Wlo bf16 split
//   blocks [768,800) : q projections  (u[b,h,:], ubias[b,h])
//   blocks [800,...) : patch extract + LN1 -> Ahi/Alo + score
// Merged so the small prep work overlaps the big extract instead of
// serializing a separate launch ahead of it.
// ---------------------------------------------------------------------------
__global__ __launch_bounds__(256) void prep_extract_kernel(
    const float* __restrict__ W_pe,
    unsigned short* __restrict__ Whi, unsigned short* __restrict__ Wlo,
    const float* __restrict__ image_embs,
    const float* __restrict__ W_proj, const float* __restrict__ b_proj,
    const float* __restrict__ in_w,   const float* __restrict__ in_b,
    float* __restrict__ u_out, float* __restrict__ bias_out,
    const float* __restrict__ im0, const float* __restrict__ im1,
    const float* __restrict__ kpts0, const float* __restrict__ kpts1,
    const float* __restrict__ scores0, const float* __restrict__ scores1,
    const int*   __restrict__ sorted_matches,
    const float* __restrict__ ln1_g, const float* __restrict__ ln1_b,
    unsigned short* __restrict__ Ahi, unsigned short* __restrict__ Alo,
    float* __restrict__ score_all)
{
  __shared__ float q1[DD];
  __shared__ float q2[DD];
  const int t = threadIdx.x;

  if (blockIdx.x < 768) {                 // ---- W conversion ----
    const int idx = blockIdx.x * 256 + t;
    const int row = idx / PD_;
    float v = (row < 255) ? W_pe[idx] : 0.0f;
    const unsigned short h = f2bf(v);
    Whi[idx] = h;
    Wlo[idx] = f2bf(v - bf2f(h));
    return;
  }

  if (blockIdx.x < 800) {                 // ---- q projections ----
    const int b = blockIdx.x - 768;
    {
      const float4* emb = (const float4*)(image_embs + (size_t)b * DIMG_);
      const float4* wr  = (const float4*)(W_proj + (size_t)t * DIMG_);
      float a = b_proj[t];
      #pragma unroll 4
      for (int i = 0; i < DIMG_ / 4; ++i) {
        const float4 e4 = emb[i], w4 = wr[i];
        a += e4.x * w4.x + e4.y * w4.y + e4.z * w4.z + e4.w * w4.w;
      }
      q1[t] = a;
    }
    __syncthreads();
    {
      const float4* wr = (const float4*)(in_w + (size_t)t * DD);
      const float4* qq = (const float4*)q1;
      float a = in_b[t];
      #pragma unroll 4
      for (int i = 0; i < DD / 4; ++i) {
        const float4 q4 = qq[i], w4 = wr[i];
        a += q4.x * w4.x + q4.y * w4.y + q4.z * w4.z + q4.w * w4.w;
      }
      q2[t] = a;
    }
    __syncthreads();
    #pragma unroll
    for (int h = 0; h < NHEADS; ++h) {
      float s = 0.0f;
      #pragma unroll 8
      for (int i = 0; i < 32; ++i)
        s += q2[h * 32 + i] * in_w[(size_t)(DD + h * 32 + i) * DD + t];
      u_out[((size_t)b * NHEADS + h) * DD + t] = s;
    }
    if (t < NHEADS) {
      float s = 0.0f;
      for (int i = 0; i < 32; ++i) s += q2[t * 32 + i] * in_b[DD + t * 32 + i];
      bias_out[b * NHEADS + t] = s;
    }
    return;
  }

  // ---- patch extract + LN1 (one wave per patch) ----
  const int L  = t & 63;
  const long gp = (long)(blockIdx.x - 800) * 4 + (t >> 6);
  const int b   = (int)(gp >> 10);
  const int n2  = (int)(gp & 1023);
  const bool side1 = (n2 >= NN);
  const float* img  = side1 ? im1 : im0;
  const float* kpts = side1 ? kpts1 : kpts0;
  const float* scrs = side1 ? scores1 : scores0;

  const int n  = side1 ? (n2 - NN) : n2;
  const int m0 = sorted_matches[((size_t)b * NN + n) * 2 + 0];
  const int m1 = sorted_matches[((size_t)b * NN + n) * 2 + 1];
  const bool valid = (m1 > -1);
  int midx = side1 ? m1 : m0;
  midx = min(max(midx, 0), MM - 1);
  const float kx = kpts[((size_t)b * MM + midx) * 2 + 0];
  const float ky = kpts[((size_t)b * MM + midx) * 2 + 1];
  const int x0 = min(max((int)rintf(kx) - 8, 0), WW - PSZ);
  const int y0 = min(max((int)rintf(ky) - 8, 0), HH - PSZ);

  float v[12];
  if (valid) {
    const size_t imb = (size_t)b * 3 * HH * WW;
    const int px = (2 * L) & 15;
    #pragma unroll
    for (int j = 0; j < 6; ++j) {
      const int p0 = 2 * L + 128 * j;
      const int c  = p0 >> 8;
      const int py = (p0 >> 4) & 15;
      const float* rp = img + imb + ((size_t)c * HH + y0 + py) * WW + x0 + px;
      v[2 * j]     = fminf(fmaxf(rp[0], 0.0f), 1.0f);
      v[2 * j + 1] = fminf(fmaxf(rp[1], 0.0f), 1.0f);
    }
  } else {
    #pragma unroll
    for (int i = 0; i < 12; ++i) v[i] = -1.0f;
  }

  float s = 0.0f, ss = 0.0f;
  #pragma unroll
  for (int i = 0; i < 12; ++i) { s += v[i]; ss += v[i] * v[i]; }
  #pragma unroll
  for (int m = 32; m; m >>= 1) { s += __shfl_xor(s, m); ss += __shfl_xor(ss, m); }
  const float mu  = s * (1.0f / 768.0f);
  const float var = ss * (1.0f / 768.0f) - mu * mu;
  const float rs  = 1.0f / sqrtf(var + 1e-5f);

  unsigned int* AhiW = (unsigned int*)(Ahi + gp * PD_);
  unsigned int* AloW = (unsigned int*)(Alo + gp * PD_);
  #pragma unroll
  for (int j = 0; j < 6; ++j) {
    const int p0 = 2 * L + 128 * j;
    const float y0e = (v[2 * j]     - mu) * rs * ln1_g[p0]     + ln1_b[p0];
    const float y1e = (v[2 * j + 1] - mu) * rs * ln1_g[p0 + 1] + ln1_b[p0 + 1];
    const unsigned short h0 = f2bf(y0e), h1 = f2bf(y1e);
    AhiW[p0 >> 1] = (unsigned int)h0 | ((unsigned int)h1 << 16);
    const unsigned short l0 = f2bf(y0e - bf2f(h0));
    const unsigned short l1 = f2bf(y1e - bf2f(h1));
    AloW[p0 >> 1] = (unsigned int)l0 | ((unsigned int)l1 << 16);
  }
  if (L == 0) {
    score_all[gp] = valid ? scrs[(size_t)b * MM + midx] : 0.0f;
  }
}

// ---------------------------------------------------------------------------
// Kernel 2: fused GEMM (e = A @ W.T, split-bf16) + LN2 + score-append +
//           logits, one 128x256 tile per block (full rows -> epilogue legal).
// 8 waves (512 thr), each wave a 64x64 sub-tile. Double-buffered LDS staging
// with the T3 "minimum 2-phase" schedule: issue next K-tile's
// global_load_lds BEFORE the ds_read+MFMA of the current one; single
// barrier per K-step (its implicit vmcnt(0) drain lands the prefetch).
// Epilogue: acc -> LDS (stride 260 = 2-way-max bank pattern both sides),
// LN2 per row with 8 lanes/row, logits vs LDS-staged u, write pe + lt.
// Saves the entire ln2_logits kernel + a 64 MB epe round-trip.
// ---------------------------------------------------------------------------
__global__ __launch_bounds__(512, 1) void gemm_fused_kernel(
    const unsigned short* __restrict__ Ahi, const unsigned short* __restrict__ Alo,
    const unsigned short* __restrict__ Whi, const unsigned short* __restrict__ Wlo,
    const float* __restrict__ b_pe,
    const float* __restrict__ ln2_g, const float* __restrict__ ln2_b,
    const float* __restrict__ score_all,
    const float* __restrict__ u, const float* __restrict__ ubias,
    float* __restrict__ pe, float* __restrict__ lt)
{
  // staging: As[2buf][2hl][128][32] = 32 KB, Bs[2buf][2hl][256][32] = 64 KB
  // epilogue aliases the same 96 KB as eb[64][260] f32 (66.6 KB)
  __shared__ __align__(16) char smem[98304];
  __shared__ float u_lds[NHEADS * DD];     // 8 KB
  __shared__ float cv_bpe[DD], cv_g[DD], cv_b[DD];
  __shared__ float ub_lds[NHEADS];

  unsigned short* const sbase = (unsigned short*)smem;
  const int t = threadIdx.x;
  const int w = t >> 6, L = t & 63;
  const int mt = blockIdx.x;               // 256 blocks, 128 rows each
  const int bidx = mt >> 3;                // batch (1024 rows / batch)

  {  // stage per-block constants (visible after first barrier)
    const float* ub0 = u + (size_t)bidx * NHEADS * DD;
    #pragma unroll
    for (int i = 0; i < 4; ++i) u_lds[t + 512 * i] = ub0[t + 512 * i];
    if (t < DD) {
      cv_bpe[t] = (t < 255) ? b_pe[t]  : 0.0f;
      cv_g[t]   = (t < 255) ? ln2_g[t] : 0.0f;
      cv_b[t]   = (t < 255) ? ln2_b[t] : 0.0f;
    }
    if (t < NHEADS) ub_lds[t] = ubias[bidx * NHEADS + t];
  }

  const int rr   = L >> 2;                      // row within 16-row chunk
  const int q_st = (L & 3) ^ ((L >> 4) & 3);    // XOR-swizzled k-quad (store)

  // 48 x 1KB staging chunks per K-step; wave w owns chunks [6w, 6w+6):
  //  [0,8)=As-hi [8,16)=As-lo [16,32)=Bs-hi [32,48)=Bs-lo
  const unsigned short* gsrc[6];
  int loff0[6], sstr[6];
  #pragma unroll
  for (int c = 0; c < 6; ++c) {
    const int cc = w * 6 + c;
    const unsigned short* sp; long row; int off, str;
    if (cc < 16) {
      sp  = (cc < 8) ? Ahi : Alo;
      row = (long)mt * 128 + (cc & 7) * 16 + rr;
      off = ((cc >> 3) * 128 + (cc & 7) * 16) * 32;           // within As buf0
      str = 8192;                                             // +16KB (ushorts)
    } else {
      const int c2 = cc - 16;
      sp  = (c2 < 16) ? Whi : Wlo;
      row = (c2 & 15) * 16 + rr;
      off = 16384 + ((c2 >> 4) * 256 + (c2 & 15) * 16) * 32;  // within Bs buf0
      str = 16384;                                            // +32KB (ushorts)
    }
    gsrc[c]  = sp + row * (long)PD_ + q_st * 8;
    loff0[c] = off;
    sstr[c]  = str;
  }

  // fragment addressing (same swizzle on read)
  const int lane_m = L & 15, quad = L >> 4;
  const int swz = quad ^ (lane_m >> 2);
  const int wr = w >> 2, wc = w & 3;
  const int am0 = wr * 64, bn0 = wc * 64;

  f32x4 acc[4][4];
  #pragma unroll
  for (int i = 0; i < 4; ++i)
    #pragma unroll
    for (int j = 0; j < 4; ++j) acc[i][j] = (f32x4){0.f, 0.f, 0.f, 0.f};

  // prologue: stage K-step 0 into buf 0
  #pragma unroll
  for (int c = 0; c < 6; ++c) gload_lds16(gsrc[c], sbase + loff0[c]);
  __syncthreads();

  for (int ks = 0; ks < PD_ / 32; ++ks) {
    const int cur = ks & 1;
    if (ks < PD_ / 32 - 1) {               // prefetch next K-step, other buf
      const int k0n = (ks + 1) * 32;
      const int nb  = cur ^ 1;
      #pragma unroll
      for (int c = 0; c < 6; ++c)
        gload_lds16(gsrc[c] + k0n, sbase + loff0[c] + nb * sstr[c]);
    }
    const unsigned short* Ab = sbase + cur * 8192;
    const unsigned short* Bb = sbase + 16384 + cur * 16384;
    bf16x8 ah[4], al[4], bh[4], bl[4];
    #pragma unroll
    for (int i = 0; i < 4; ++i) {
      const int ra = (am0 + i * 16 + lane_m) * 32 + swz * 8;
      ah[i] = *(const bf16x8*)(Ab + ra);
      al[i] = *(const bf16x8*)(Ab + 4096 + ra);     // lo half: +128*32
      const int rb = (bn0 + i * 16 + lane_m) * 32 + swz * 8;
      bh[i] = *(const bf16x8*)(Bb + rb);
      bl[i] = *(const bf16x8*)(Bb + 8192 + rb);     // lo half: +256*32
    }
    #pragma unroll
    for (int i = 0; i < 4; ++i)
      #pragma unroll
      for (int j = 0; j < 4; ++j) {
        acc[i][j] = __builtin_amdgcn_mfma_f32_16x16x32_bf16(ah[i], bh[j], acc[i][j], 0, 0, 0);
        acc[i][j] = __builtin_amdgcn_mfma_f32_16x16x32_bf16(ah[i], bl[j], acc[i][j], 0, 0, 0);
        acc[i][j] = __builtin_amdgcn_mfma_f32_16x16x32_bf16(al[i], bh[j], acc[i][j], 0, 0, 0);
      }
    __syncthreads();   // implicit vmcnt(0): prefetch landed; buf reads done
  }

  // ---- fused epilogue: two 64-row halves through LDS ----
  float* const eb = (float*)smem;          // [64][260] f32, aliases staging
  const int r8 = t >> 3, l8 = t & 7;       // 8 lanes per row, 64 rows
  #pragma unroll
  for (int hh = 0; hh < 2; ++hh) {
    if (hh) __syncthreads();               // half-0 readers done before overwrite
    if (wr == hh) {
      // C/D layout col=lane&15, row=quad*4+reg  [verified m89/m91]
      #pragma unroll
      for (int i = 0; i < 4; ++i)
        #pragma unroll
        for (int j = 0; j < 4; ++j)
          #pragma unroll
          for (int v = 0; v < 4; ++v)
            eb[(i * 16 + quad * 4 + v) * 260 + bn0 + j * 16 + lane_m] = acc[i][j][v];
    }
    __syncthreads();

    const long grow = (long)mt * 128 + hh * 64 + r8;
    float x[32];
    float s = 0.0f, ss = 0.0f;
    #pragma unroll
    for (int j = 0; j < 32; ++j) {
      const int c = l8 + 8 * j;
      float vv = eb[r8 * 260 + c];
      if (c < 255) { vv += cv_bpe[c]; s += vv; ss += vv * vv; }
      x[j] = vv;
    }
    s += __shfl_xor(s, 1); ss += __shfl_xor(ss, 1);
    s += __shfl_xor(s, 2); ss += __shfl_xor(ss, 2);
    s += __shfl_xor(s, 4); ss += __shfl_xor(ss, 4);
    const float mu  = s * (1.0f / 255.0f);
    const float var = ss * (1.0f / 255.0f) - mu * mu;
    const float rs  = 1.0f / sqrtf(var + 1e-5f);

    float scrow = 0.0f;
    if (l8 == 7) scrow = score_all[grow];  // only lane holding c==255 needs it

    float d[NHEADS] = {0, 0, 0, 0, 0, 0, 0, 0};
    float* const per = pe + grow * DD;
    #pragma unroll
    for (int j = 0; j < 32; ++j) {
      const int c = l8 + 8 * j;
      const float y = (c < 255) ? (x[j] - mu) * rs * cv_g[c] + cv_b[c] : scrow;
      per[c] = y;
      #pragma unroll
      for (int h = 0; h < NHEADS; ++h) d[h] += y * u_lds[h * DD + c];
    }
    #pragma unroll
    for (int h = 0; h < NHEADS; ++h) {
      d[h] += __shfl_xor(d[h], 1);
      d[h] += __shfl_xor(d[h], 2);
      d[h] += __shfl_xor(d[h], 4);
    }
    // lane l8 writes head l8 (select chain: keep d[] in registers, rule #20)
    const float dv = (l8 == 0) ? d[0] : (l8 == 1) ? d[1] : (l8 == 2) ? d[2] :
                     (l8 == 3) ? d[3] : (l8 == 4) ? d[4] : (l8 == 5) ? d[5] :
                     (l8 == 6) ? d[6] : d[7];
    lt[grow * NHEADS + l8] = (dv + ub_lds[l8]) * 0.17677669529663687f; // 1/sqrt(32)
  }
}

// ---------------------------------------------------------------------------
// Kernel 3: fused softmax + partial ctx over 64-key chunks (16 chunks ->
// 512 blocks = 2 blocks/CU for latency hiding; softmax redundant per block,
// logits are L2-resident).
// ---------------------------------------------------------------------------
__global__ __launch_bounds__(256) void ctx_kernel(
    const float* __restrict__ pe, const float* __restrict__ lt,
    float* __restrict__ ctxp)
{
  __shared__ __align__(16) float pr[TWO_N][NHEADS];   // 32 KB probs
  const int b = blockIdx.x, ch = blockIdx.y, t = threadIdx.x;

  {
    const int h = t >> 5, l = t & 31;
    const float* base = lt + (size_t)b * TWO_N * NHEADS + h;
    float v[32];
    float mx = -1e30f;
    #pragma unroll 8
    for (int i = 0; i < 32; ++i) { v[i] = base[(l + 32 * i) * NHEADS]; mx = fmaxf(mx, v[i]); }
    #pragma unroll
    for (int m = 16; m; m >>= 1) mx = fmaxf(mx, __shfl_xor(mx, m, 32));
    float sm = 0.0f;
    #pragma unroll 8
    for (int i = 0; i < 32; ++i) { v[i] = expf(v[i] - mx); sm += v[i]; }
    #pragma unroll
    for (int m = 16; m; m >>= 1) sm += __shfl_xor(sm, m, 32);
    const float inv = 1.0f / sm;
    #pragma unroll 8
    for (int i = 0; i < 32; ++i) pr[l + 32 * i][h] = v[i] * inv;
  }
  __syncthreads();

  const float* peb = pe + ((size_t)b * TWO_N + ch * 64) * DD;
  float acc[NHEADS] = {0, 0, 0, 0, 0, 0, 0, 0};
  #pragma unroll 4
  for (int k = 0; k < 64; ++k) {
    const float v = peb[(size_t)k * DD + t];                 // coalesced
    const float4 a0 = *(const float4*)&pr[ch * 64 + k][0];   // LDS broadcast
    const float4 a1 = *(const float4*)&pr[ch * 64 + k][4];
    acc[0] += a0.x * v; acc[1] += a0.y * v; acc[2] += a0.z * v; acc[3] += a0.w * v;
    acc[4] += a1.x * v; acc[5] += a1.y * v; acc[6] += a1.z * v; acc[7] += a1.w * v;
  }
  #pragma unroll
  for (int h = 0; h < NHEADS; ++h)
    ctxp[(((size_t)b * CHCT + ch) * NHEADS + h) * DD + t] = acc[h];
}

// ---------------------------------------------------------------------------
// Kernel 4: reduce ctx partials + Wv + out_w + W_fc head
// ---------------------------------------------------------------------------
__global__ __launch_bounds__(256) void final_kernel(
    const float* __restrict__ ctxp,
    const float* __restrict__ in_w,  const float* __restrict__ in_b,
    const float* __restrict__ out_w, const float* __restrict__ out_b,
    const float* __restrict__ W_fc,  const float* __restrict__ b_fc,
    float* __restrict__ outp)
{
  __shared__ __align__(16) float ctx_sh[NHEADS * DD];
  __shared__ __align__(16) float o_sh[DD], o2_sh[DD];
  const int t = threadIdx.x;
  const int b = blockIdx.x;

  #pragma unroll
  for (int h = 0; h < NHEADS; ++h) {
    float s = 0.0f;
    #pragma unroll
    for (int ch = 0; ch < CHCT; ++ch)
      s += ctxp[(((size_t)b * CHCT + ch) * NHEADS + h) * DD + t];
    ctx_sh[h * DD + t] = s;
  }
  __syncthreads();
  {
    const float4* wv = (const float4*)(in_w + (size_t)(2 * DD + t) * DD);
    const float4* cx = (const float4*)(ctx_sh + (t >> 5) * DD);
    float o1 = in_b[2 * DD + t];
    #pragma unroll 4
    for (int j = 0; j < DD / 4; ++j) {
      const float4 w4 = wv[j], c4 = cx[j];
      o1 += w4.x * c4.x + w4.y * c4.y + w4.z * c4.z + w4.w * c4.w;
    }
    o_sh[t] = o1;
  }
  __syncthreads();
  {
    const float4* wr = (const float4*)(out_w + (size_t)t * DD);
    const float4* oo = (const float4*)o_sh;
    float o2 = out_b[t];
    #pragma unroll 4
    for (int j = 0; j < DD / 4; ++j) {
      const float4 w4 = wr[j], c4 = oo[j];
      o2 += w4.x * c4.x + w4.y * c4.y + w4.z * c4.z + w4.w * c4.w;
    }
    o2_sh[t] = o2;
  }
  __syncthreads();
  if (t < 6) {
    const float4* wr = (const float4*)(W_fc + (size_t)t * DD);
    const float4* oo = (const float4*)o2_sh;
    float r = b_fc[t];
    for (int j = 0; j < DD / 4; ++j) {
      const float4 w4 = wr[j], c4 = oo[j];
      r += w4.x * c4.x + w4.y * c4.y + w4.z * c4.z + w4.w * c4.w;
    }
    outp[b * 6 + t] = r;
  }
}

// ---------------------------------------------------------------------------
extern "C" void kernel_launch(void* const* d_in, const int* in_sizes, int n_in,
                              void* d_out, int out_size, void* d_ws, size_t ws_size,
                              hipStream_t stream) {
  const float* im0       = (const float*)d_in[0];
  const float* im1       = (const float*)d_in[1];
  const float* kpts0     = (const float*)d_in[2];
  const float* kpts1     = (const float*)d_in[3];
  const float* scores0   = (const float*)d_in[4];
  const float* scores1   = (const float*)d_in[5];
  const float* image_embs= (const float*)d_in[6];
  const int*   smatch    = (const int*)d_in[7];
  const float* ln1_g     = (const float*)d_in[8];
  const float* ln1_b     = (const float*)d_in[9];
  const float* W_pe      = (const float*)d_in[10];
  const float* b_pe      = (const float*)d_in[11];
  const float* ln2_g     = (const float*)d_in[12];
  const float* ln2_b     = (const float*)d_in[13];
  const float* W_proj    = (const float*)d_in[14];
  const float* b_proj    = (const float*)d_in[15];
  const float* in_w      = (const float*)d_in[16];
  const float* in_b      = (const float*)d_in[17];
  const float* out_w     = (const float*)d_in[18];
  const float* out_b     = (const float*)d_in[19];
  const float* W_fc      = (const float*)d_in[20];
  const float* b_fc      = (const float*)d_in[21];

  // ---- workspace layout (bytes) ----
  char* ws = (char*)d_ws;
  size_t off = 0;
  float* epe   = (float*)(ws + off); off += (size_t)ROWS_TOT * DD * 4;        // 32 MB (pe)
  float* u     = (float*)(ws + off); off += (size_t)BB * NHEADS * DD * 4;     // 256 KB
  float* ubias = (float*)(ws + off); off += (size_t)BB * NHEADS * 4;
  off = (off + 1023) & ~(size_t)1023;
  float* score = (float*)(ws + off); off += (size_t)ROWS_TOT * 4;             // 128 KB
  float* lt    = (float*)(ws + off); off += (size_t)BB * TWO_N * NHEADS * 4;  // 1 MB
  float* ctxp  = (float*)(ws + off); off += (size_t)BB * CHCT * NHEADS * DD * 4; // 4 MB
  unsigned short* Whi = (unsigned short*)(ws + off); off += (size_t)256 * PD_ * 2;
  unsigned short* Wlo = (unsigned short*)(ws + off); off += (size_t)256 * PD_ * 2;
  off = (off + 1023) & ~(size_t)1023;
  unsigned short* Ahi = (unsigned short*)(ws + off); off += (size_t)ROWS_TOT * PD_ * 2; // 50 MB
  unsigned short* Alo = (unsigned short*)(ws + off); off += (size_t)ROWS_TOT * PD_ * 2; // 50 MB

  prep_extract_kernel<<<800 + ROWS_TOT / 4, 256, 0, stream>>>(
      W_pe, Whi, Wlo, image_embs, W_proj, b_proj, in_w, in_b, u, ubias,
      im0, im1, kpts0, kpts1, scores0, scores1, smatch,
      ln1_g, ln1_b, Ahi, Alo, score);
  gemm_fused_kernel<<<ROWS_TOT / 128, 512, 0, stream>>>(
      Ahi, Alo, Whi, Wlo, b_pe, ln2_g, ln2_b, score, u, ubias, epe, lt);
  ctx_kernel<<<dim3(BB, CHCT), 256, 0, stream>>>(epe, lt, ctxp);
  final_kernel<<<BB, 256, 0, stream>>>(ctxp, in_w, in_b, out_w, out_b,
                                       W_fc, b_fc, (float*)d_out);
}